// Round 1
// baseline (1308.691 us; speedup 1.0000x reference)
//
#include <hip/hip_runtime.h>
#include <math.h>

namespace {

constexpr int S_ = 1024;
constexpr int B_ = 64;
constexpr int D_ = 64;
constexpr float SCALE = 0.125f;  // 1/sqrt(64)

// ---------------------------------------------------------------------------
// Kernel A: bias[b,qp,k] = sum_d Q[b,qp,d] * R_k[qp,k,d]   (only k <= qp)
// Written into the attn region of d_out (used as scratch; kernel B consumes
// it and overwrites it with the final attn values).
// Grid: (4 k-chunks of 256, S qp).  Block: 256 threads.
// ---------------------------------------------------------------------------
__global__ __launch_bounds__(256) void bias_kernel(
    const float* __restrict__ q, const float* __restrict__ Rk,
    float* __restrict__ attn) {
  const int qp = (S_ - 1) - (int)blockIdx.y;  // big rows first (load balance)
  const int chunk = blockIdx.x;
  if (chunk * 256 > qp) return;  // uniform exit

  __shared__ float Qs[64][65];  // [b][d], +1 pad
  __shared__ float Rs[64][65];  // [k][d], +1 pad
  const int t = threadIdx.x;

  // stage Q[:, qp, :]  (64 b x 64 d)
  for (int i = 0; i < 16; ++i) {
    const int flat = t + i * 256;
    const int b = flat >> 6, d = flat & 63;
    Qs[b][d] = q[((b << 10) + qp) * 64 + d];
  }

  const int k0 = (t & 15) * 4;  // 4 k per thread
  const int b0 = (t >> 4) * 4;  // 4 b per thread

  for (int s = 0; s < 4; ++s) {
    const int kb = chunk * 256 + s * 64;
    if (kb > qp) break;  // uniform
    __syncthreads();
    // stage R_k[qp, kb..kb+63, :]
    for (int i = 0; i < 4; ++i) {
      const int flat = t + i * 256;  // float4 index over 64x64
      const int kk = flat >> 4, dd = (flat & 15) * 4;
      const float4 r4 = *(const float4*)(Rk + ((qp << 10) + kb + kk) * 64 + dd);
      Rs[kk][dd + 0] = r4.x; Rs[kk][dd + 1] = r4.y;
      Rs[kk][dd + 2] = r4.z; Rs[kk][dd + 3] = r4.w;
    }
    __syncthreads();

    float acc[4][4];  // [k][b]
    #pragma unroll
    for (int i = 0; i < 4; ++i)
      #pragma unroll
      for (int j = 0; j < 4; ++j) acc[i][j] = 0.f;

    for (int d = 0; d < 64; ++d) {
      float rk[4], qv[4];
      #pragma unroll
      for (int i = 0; i < 4; ++i) rk[i] = Rs[k0 + i][d];
      #pragma unroll
      for (int j = 0; j < 4; ++j) qv[j] = Qs[b0 + j][d];
      #pragma unroll
      for (int i = 0; i < 4; ++i)
        #pragma unroll
        for (int j = 0; j < 4; ++j) acc[i][j] += rk[i] * qv[j];
    }

    #pragma unroll
    for (int j = 0; j < 4; ++j) {
      const int b = b0 + j;
      float* row = attn + (((b << 10) + qp) << 10) + kb + k0;
      if (kb + k0 + 3 <= qp) {
        *(float4*)row = make_float4(acc[0][j], acc[1][j], acc[2][j], acc[3][j]);
      } else {
        for (int i = 0; i < 4; ++i)
          if (kb + k0 + i <= qp) row[i] = acc[i][j];
      }
    }
  }
}

// ---------------------------------------------------------------------------
// Kernel B: per (b, 64-row q tile): scores = (QK^T + bias)*SCALE, causal
// softmax (two passes over k; pass 2 recomputes scores bit-identically),
// writes normalized attn (overwriting the bias scratch in place) and
// accumulates out = attn @ V.  Zero-fills attn above the processed tiles.
// Grid: (16 q-tiles, 64 b).  Block: 256 threads.
// ---------------------------------------------------------------------------
__global__ __launch_bounds__(256) void attn_kernel(
    const float* __restrict__ qg, const float* __restrict__ kg,
    const float* __restrict__ vg, float* attn, float* __restrict__ outg) {
  const int b = blockIdx.y;
  const int qti = 15 - (int)blockIdx.x;  // big tiles first
  const int qb = qti * 64;

  __shared__ float Qs[64][65];   // [q][d]
  __shared__ float KVs[64][65];  // [k][d] (K, then reused for V)
  __shared__ float Ps[64][65];   // [q][k] normalized attn tile
  __shared__ float redm[64][16];
  __shared__ float redl[64][16];

  const int t = threadIdx.x;
  const int k0 = (t & 15) * 4;  // score phase: 4 k per thread
  const int q0 = (t >> 4) * 4;  // 4 q per thread (same rows in PV phase)
  const int d0 = k0;            // PV phase: 4 d per thread

  for (int i = 0; i < 16; ++i) {
    const int flat = t + i * 256;
    const int qq = flat >> 6, d = flat & 63;
    Qs[qq][d] = qg[((b << 10) + qb + qq) * 64 + d];
  }

  float m[4], l[4];
  #pragma unroll
  for (int j = 0; j < 4; ++j) { m[j] = -INFINITY; l[j] = 0.f; }

  const int ntiles = qti + 1;

  // ---------------- pass 1: row max & sum of exp ----------------
  for (int tt = 0; tt < ntiles; ++tt) {
    const int kb = tt * 64;
    __syncthreads();
    for (int i = 0; i < 4; ++i) {
      const int flat = t + i * 256;
      const int kk = flat >> 4, dd = (flat & 15) * 4;
      const float4 r4 = *(const float4*)(kg + ((b << 10) + kb + kk) * 64 + dd);
      KVs[kk][dd + 0] = r4.x; KVs[kk][dd + 1] = r4.y;
      KVs[kk][dd + 2] = r4.z; KVs[kk][dd + 3] = r4.w;
    }
    __syncthreads();

    float acc[4][4];  // [q][k]
    #pragma unroll
    for (int j = 0; j < 4; ++j)
      #pragma unroll
      for (int i = 0; i < 4; ++i) acc[j][i] = 0.f;
    for (int d = 0; d < 64; ++d) {
      float kv[4], qv[4];
      #pragma unroll
      for (int i = 0; i < 4; ++i) kv[i] = KVs[k0 + i][d];
      #pragma unroll
      for (int j = 0; j < 4; ++j) qv[j] = Qs[q0 + j][d];
      #pragma unroll
      for (int j = 0; j < 4; ++j)
        #pragma unroll
        for (int i = 0; i < 4; ++i) acc[j][i] += qv[j] * kv[i];
    }

    #pragma unroll
    for (int j = 0; j < 4; ++j) {
      const int qq = qb + q0 + j;
      const float4 b4 = *(const float4*)(attn + (((b << 10) + qq) << 10) + kb + k0);
      const float barr[4] = {b4.x, b4.y, b4.z, b4.w};
      float sv[4];
      float tmax = -INFINITY;
      #pragma unroll
      for (int i = 0; i < 4; ++i) {
        sv[i] = (acc[j][i] + barr[i]) * SCALE;
        if (kb + k0 + i <= qq) tmax = fmaxf(tmax, sv[i]);
      }
      if (tmax > -INFINITY) {
        const float mnew = fmaxf(m[j], tmax);
        float ladd = 0.f;
        #pragma unroll
        for (int i = 0; i < 4; ++i)
          if (kb + k0 + i <= qq) ladd += __expf(sv[i] - mnew);
        l[j] = l[j] * __expf(m[j] - mnew) + ladd;
        m[j] = mnew;
      }
    }
  }

  // ---------------- reduce m,l across the 16 k-slot threads ----------------
  __syncthreads();
  #pragma unroll
  for (int j = 0; j < 4; ++j) {
    redm[q0 + j][t & 15] = m[j];
    redl[q0 + j][t & 15] = l[j];
  }
  __syncthreads();
  float mf[4], linv[4];
  #pragma unroll
  for (int j = 0; j < 4; ++j) {
    float mm = -INFINITY;
    for (int i = 0; i < 16; ++i) mm = fmaxf(mm, redm[q0 + j][i]);
    float ll = 0.f;
    for (int i = 0; i < 16; ++i) ll += redl[q0 + j][i] * __expf(redm[q0 + j][i] - mm);
    mf[j] = mm;
    linv[j] = 1.f / ll;
  }

  // ---------------- pass 2: write attn + accumulate PV ----------------
  float accpv[4][4];  // [q][d]
  #pragma unroll
  for (int j = 0; j < 4; ++j)
    #pragma unroll
    for (int i = 0; i < 4; ++i) accpv[j][i] = 0.f;

  for (int tt = 0; tt < ntiles; ++tt) {
    const int kb = tt * 64;
    __syncthreads();
    for (int i = 0; i < 4; ++i) {
      const int flat = t + i * 256;
      const int kk = flat >> 4, dd = (flat & 15) * 4;
      const float4 r4 = *(const float4*)(kg + ((b << 10) + kb + kk) * 64 + dd);
      KVs[kk][dd + 0] = r4.x; KVs[kk][dd + 1] = r4.y;
      KVs[kk][dd + 2] = r4.z; KVs[kk][dd + 3] = r4.w;
    }
    __syncthreads();

    float acc[4][4];  // identical recompute to pass 1
    #pragma unroll
    for (int j = 0; j < 4; ++j)
      #pragma unroll
      for (int i = 0; i < 4; ++i) acc[j][i] = 0.f;
    for (int d = 0; d < 64; ++d) {
      float kv[4], qv[4];
      #pragma unroll
      for (int i = 0; i < 4; ++i) kv[i] = KVs[k0 + i][d];
      #pragma unroll
      for (int j = 0; j < 4; ++j) qv[j] = Qs[q0 + j][d];
      #pragma unroll
      for (int j = 0; j < 4; ++j)
        #pragma unroll
        for (int i = 0; i < 4; ++i) acc[j][i] += qv[j] * kv[i];
    }

    #pragma unroll
    for (int j = 0; j < 4; ++j) {
      const int qq = qb + q0 + j;
      float* arow = attn + (((b << 10) + qq) << 10) + kb + k0;
      const float4 b4 = *(const float4*)arow;
      const float barr[4] = {b4.x, b4.y, b4.z, b4.w};
      float p[4];
      #pragma unroll
      for (int i = 0; i < 4; ++i) {
        const float s = (acc[j][i] + barr[i]) * SCALE;
        p[i] = (kb + k0 + i <= qq) ? __expf(s - mf[j]) * linv[j] : 0.f;
      }
      *(float4*)arow = make_float4(p[0], p[1], p[2], p[3]);
      #pragma unroll
      for (int i = 0; i < 4; ++i) Ps[q0 + j][k0 + i] = p[i];
    }
    __syncthreads();
    // stage V over the K buffer
    for (int i = 0; i < 4; ++i) {
      const int flat = t + i * 256;
      const int kk = flat >> 4, dd = (flat & 15) * 4;
      const float4 r4 = *(const float4*)(vg + ((b << 10) + kb + kk) * 64 + dd);
      KVs[kk][dd + 0] = r4.x; KVs[kk][dd + 1] = r4.y;
      KVs[kk][dd + 2] = r4.z; KVs[kk][dd + 3] = r4.w;
    }
    __syncthreads();
    for (int kk = 0; kk < 64; ++kk) {
      float pv[4], vv[4];
      #pragma unroll
      for (int j = 0; j < 4; ++j) pv[j] = Ps[q0 + j][kk];
      #pragma unroll
      for (int i = 0; i < 4; ++i) vv[i] = KVs[kk][d0 + i];
      #pragma unroll
      for (int j = 0; j < 4; ++j)
        #pragma unroll
        for (int i = 0; i < 4; ++i) accpv[j][i] += pv[j] * vv[i];
    }
  }

  // ---------------- zero-fill attn for k >= ntiles*64 ----------------
  for (int kb = ntiles * 64; kb < S_; kb += 64) {
    #pragma unroll
    for (int j = 0; j < 4; ++j) {
      const int qq = qb + q0 + j;
      *(float4*)(attn + (((b << 10) + qq) << 10) + kb + k0) =
          make_float4(0.f, 0.f, 0.f, 0.f);
    }
  }

  // ---------------- store out (already normalized) ----------------
  #pragma unroll
  for (int j = 0; j < 4; ++j) {
    const int qq = qb + q0 + j;
    *(float4*)(outg + ((b << 10) + qq) * 64 + d0) =
        make_float4(accpv[j][0], accpv[j][1], accpv[j][2], accpv[j][3]);
  }
}

// ---------------------------------------------------------------------------
// Kernel C: out[b,qp,:] += sum_k attn[b,qp,k] * R_v[qp,k,:]
// M = batch so R_v is read exactly once.  attn is 0 above the diagonal, so
// boundary tiles need no masking.
// Grid: (S qp).  Block: 256 threads.
// ---------------------------------------------------------------------------
__global__ __launch_bounds__(256) void rvout_kernel(
    const float* __restrict__ Rv, const float* __restrict__ attn,
    float* outg) {
  const int qp = (S_ - 1) - (int)blockIdx.x;  // big rows first
  __shared__ float As[64][65];  // [b][k]
  __shared__ float Rs[64][65];  // [k][d]
  const int t = threadIdx.x;
  const int d0 = (t & 15) * 4;
  const int b0 = (t >> 4) * 4;

  float acc[4][4];  // [b][d]
  #pragma unroll
  for (int j = 0; j < 4; ++j)
    #pragma unroll
    for (int i = 0; i < 4; ++i) acc[j][i] = 0.f;

  const int ntiles = (qp >> 6) + 1;
  for (int tt = 0; tt < ntiles; ++tt) {
    const int kb = tt * 64;
    __syncthreads();
    for (int i = 0; i < 4; ++i) {
      const int flat = t + i * 256;
      const int r = flat >> 4, c4 = (flat & 15) * 4;
      const float4 a4 = *(const float4*)(attn + (((r << 10) + qp) << 10) + kb + c4);
      As[r][c4 + 0] = a4.x; As[r][c4 + 1] = a4.y;
      As[r][c4 + 2] = a4.z; As[r][c4 + 3] = a4.w;
      const float4 r4 = *(const float4*)(Rv + ((qp << 10) + kb + r) * 64 + c4);
      Rs[r][c4 + 0] = r4.x; Rs[r][c4 + 1] = r4.y;
      Rs[r][c4 + 2] = r4.z; Rs[r][c4 + 3] = r4.w;
    }
    __syncthreads();
    for (int kk = 0; kk < 64; ++kk) {
      float av[4], rv[4];
      #pragma unroll
      for (int j = 0; j < 4; ++j) av[j] = As[b0 + j][kk];
      #pragma unroll
      for (int i = 0; i < 4; ++i) rv[i] = Rs[kk][d0 + i];
      #pragma unroll
      for (int j = 0; j < 4; ++j)
        #pragma unroll
        for (int i = 0; i < 4; ++i) acc[j][i] += av[j] * rv[i];
    }
  }

  #pragma unroll
  for (int j = 0; j < 4; ++j) {
    float* po = outg + (((b0 + j) << 10) + qp) * 64 + d0;
    float4 o = *(const float4*)po;
    o.x += acc[j][0]; o.y += acc[j][1]; o.z += acc[j][2]; o.w += acc[j][3];
    *(float4*)po = o;
  }
}

}  // namespace

extern "C" void kernel_launch(void* const* d_in, const int* in_sizes, int n_in,
                              void* d_out, int out_size, void* d_ws, size_t ws_size,
                              hipStream_t stream) {
  const float* q  = (const float*)d_in[0];
  const float* k  = (const float*)d_in[1];
  const float* v  = (const float*)d_in[2];
  const float* Rk = (const float*)d_in[3];
  const float* Rv = (const float*)d_in[4];
  // d_in[5] = mask (causal tril), d_in[6] = one_direction (==1): hardcoded.

  float* out  = (float*)d_out;
  float* attn = out + (size_t)B_ * S_ * D_;  // second output, also bias scratch

  hipLaunchKernelGGL(bias_kernel, dim3(4, S_), dim3(256), 0, stream, q, Rk, attn);
  hipLaunchKernelGGL(attn_kernel, dim3(16, B_), dim3(256), 0, stream, q, k, v, attn, out);
  hipLaunchKernelGGL(rvout_kernel, dim3(S_), dim3(256), 0, stream, Rv, attn, out);
}